// Round 25
// baseline (158.886 us; speedup 1.0000x reference)
//
#include <hip/hip_runtime.h>

// Problem constants
#define LQ  512
#define LKN 512
#define BB  32
#define DD  768

typedef float    f4     __attribute__((ext_vector_type(4)));
typedef _Float16 half8  __attribute__((ext_vector_type(8)));
typedef _Float16 half4  __attribute__((ext_vector_type(4)));
typedef __fp16   fp16x2 __attribute__((ext_vector_type(2)));

union H8 { half8 h; unsigned int u[4]; };

__device__ __forceinline__ unsigned int pk2(float a, float b) {
    union { fp16x2 h; unsigned int u; } c;
    c.h = __builtin_amdgcn_cvt_pkrtz(a, b);
    return c.u;
}
__device__ __forceinline__ half8 cvt8(f4 a, f4 b) {
    H8 r;
    r.u[0] = pk2(a[0], a[1]); r.u[1] = pk2(a[2], a[3]);
    r.u[2] = pk2(b[0], b[1]); r.u[3] = pk2(b[2], b[3]);
    return r.h;
}

// Forced-in-flight global loads (volatile asm cannot be sunk by the scheduler).
__device__ __forceinline__ void gload16(half8& dst, const _Float16* p) {
    asm volatile("global_load_dwordx4 %0, %1, off" : "=v"(dst) : "v"(p));
}
__device__ __forceinline__ void gloadf4(f4& dst, const float* p) {
    asm volatile("global_load_dwordx4 %0, %1, off" : "=v"(dst) : "v"(p));
}

// ---------------------------------------------------------------------------
// prep_pack: 3072 blocks x 512 threads, 64 l x 128 d per block.
// r25 change: XF/XV stores are NON-TEMPORAL (bypass L2 write-allocate;
// prep moves 147MB HBM at only 2.5 TB/s while nt-writing fill hits 6.9).
// RNE conversion via (_Float16) casts.
// ---------------------------------------------------------------------------
__global__ __launch_bounds__(512)
void prep_pack(const float* __restrict__ x1, const float* __restrict__ x2,
               _Float16* __restrict__ xf1, _Float16* __restrict__ xf2,
               _Float16* __restrict__ xv1, _Float16* __restrict__ xv2)
{
    const int bi   = blockIdx.x;            // 3072
    const int side = bi / 1536;
    const int rem  = bi % 1536;
    const int b    = rem / 48;
    const int rem2 = rem % 48;
    const int l0   = (rem2 / 6) * 64;
    const int d0   = (rem2 % 6) * 128;

    const float* __restrict__ X  = side ? x2  : x1;
    _Float16* __restrict__    XF = side ? xf2 : xf1;
    _Float16* __restrict__    XV = side ? xv2 : xv1;

    __shared__ _Float16 T[64][136];         // 64 x 128 data + pad

    const int tid = threadIdx.x;            // 0..511
    {
        const int r  = tid >> 4;            // 0..31
        const int c8 = (tid & 15) * 8;      // 0..120
        const float* src = X + ((size_t)(l0 + r) * BB + b) * DD + d0 + c8;
        f4 v0, v1, v2, v3;
        gloadf4(v0, src);
        gloadf4(v1, src + 4);
        gloadf4(v2, src + (size_t)32 * BB * DD);        // row r+32
        gloadf4(v3, src + (size_t)32 * BB * DD + 4);
        asm volatile("s_waitcnt vmcnt(2)" ::: "memory"); // first row pair done
        __builtin_amdgcn_sched_barrier(0);
        {
            half4 ha, hb;
            ha[0] = (_Float16)v0[0]; ha[1] = (_Float16)v0[1];
            ha[2] = (_Float16)v0[2]; ha[3] = (_Float16)v0[3];
            hb[0] = (_Float16)v1[0]; hb[1] = (_Float16)v1[1];
            hb[2] = (_Float16)v1[2]; hb[3] = (_Float16)v1[3];
            *(half4*)&T[r][c8]     = ha;
            *(half4*)&T[r][c8 + 4] = hb;
        }
        asm volatile("s_waitcnt vmcnt(0)" ::: "memory");
        __builtin_amdgcn_sched_barrier(0);
        {
            half4 ha, hb;
            ha[0] = (_Float16)v2[0]; ha[1] = (_Float16)v2[1];
            ha[2] = (_Float16)v2[2]; ha[3] = (_Float16)v2[3];
            hb[0] = (_Float16)v3[0]; hb[1] = (_Float16)v3[1];
            hb[2] = (_Float16)v3[2]; hb[3] = (_Float16)v3[3];
            *(half4*)&T[r + 32][c8]     = ha;
            *(half4*)&T[r + 32][c8 + 4] = hb;
        }
    }
    __syncthreads();
    // XF: fragment-packed (A/B operand for QK^T): 1024 chunks, 2 per thread
    #pragma unroll
    for (int c2 = tid; c2 < 1024; c2 += 512) {
        const int dhalf = c2 >> 9;          // 0..1
        const int t16l  = (c2 >> 7) & 3;
        const int ksl   = (c2 >> 6) & 1;
        const int ln    = c2 & 63;
        half8 v = *(const half8*)&T[t16l * 16 + (ln & 15)][dhalf * 64 + ksl * 32 + (ln >> 4) * 8];
        const size_t t16g = (size_t)(l0 >> 4) + t16l;
        const size_t ksg  = (size_t)(d0 >> 5) + dhalf * 2 + ksl;
        __builtin_nontemporal_store(v,
            (half8*)(XF + (((size_t)b * 32 + t16g) * 24 + ksg) * 512 + ln * 8));
    }
    // XV: B-fragment-packed V: 1024 chunks, 2 per thread
    #pragma unroll
    for (int c2 = tid; c2 < 1024; c2 += 512) {
        const int dtl  = c2 >> 7;           // 0..7
        const int ks2l = (c2 >> 6) & 1;
        const int ln   = c2 & 63;
        half8 v;
        #pragma unroll
        for (int jj = 0; jj < 8; ++jj)
            v[jj] = T[ks2l * 32 + (ln >> 4) * 8 + jj][dtl * 16 + (ln & 15)];
        const size_t dtg  = (size_t)(d0 >> 4) + dtl;
        const size_t ks2g = (size_t)(l0 >> 5) + ks2l;
        __builtin_nontemporal_store(v,
            (half8*)(XV + (((size_t)b * 48 + dtg) * 16 + ks2g) * 512 + ln * 8));
    }
}

// ---------------------------------------------------------------------------
// Stage 1: S = x1.x2^T (f32), 128x128 tile/block, no LDS.
// ---------------------------------------------------------------------------
__global__ __launch_bounds__(256, 3)
void gemm_s(const _Float16* __restrict__ xf1, const _Float16* __restrict__ xf2,
            float* __restrict__ S)
{
    const int i   = blockIdx.x;            // 512
    const int xcd = i & 7;
    const int j   = i >> 3;                // 0..63
    const int t   = j & 15;                // tile fastest
    const int b   = xcd * 4 + (j >> 4);    // b slowest
    const int lt  = t >> 2, mt = t & 3;
    const int l0b = lt * 128, m0b = mt * 128;

    const int tid  = threadIdx.x;
    const int lane = tid & 63;
    const int w    = tid >> 6;
    const int wl   = w >> 1, wm = w & 1;
    const int lr   = lane & 15;
    const int lg   = lane >> 4;

    f4 acc[16];
    #pragma unroll
    for (int t2 = 0; t2 < 16; ++t2) acc[t2] = f4{0.f, 0.f, 0.f, 0.f};

    {
        const _Float16* ab = xf1 + (((size_t)b * 32 + lt * 8 + wl * 4) * 24) * 512 + lane * 8;
        const _Float16* bb = xf2 + (((size_t)b * 32 + mt * 8 + wm * 4) * 24) * 512 + lane * 8;
        __builtin_amdgcn_s_setprio(1);
        #pragma unroll
        for (int ks = 0; ks < 24; ++ks) {
            half8 aF[4], bF[4];
            #pragma unroll
            for (int q = 0; q < 4; ++q) {
                aF[q] = *(const half8*)(ab + ((size_t)q * 24 + ks) * 512);
                bF[q] = *(const half8*)(bb + ((size_t)q * 24 + ks) * 512);
            }
            #pragma unroll
            for (int q = 0; q < 4; ++q)
                #pragma unroll
                for (int p = 0; p < 4; ++p)
                    acc[q * 4 + p] = __builtin_amdgcn_mfma_f32_16x16x32_f16(aF[q], bF[p], acc[q * 4 + p], 0, 0, 0);
        }
        __builtin_amdgcn_s_setprio(0);
    }

    {
        float* srow = S + ((size_t)b * 512 + l0b + wl * 64) * 512 + m0b + wm * 64;
        #pragma unroll
        for (int q = 0; q < 4; ++q)
            #pragma unroll
            for (int p = 0; p < 4; ++p)
                #pragma unroll
                for (int r = 0; r < 4; ++r)
                    srow[(size_t)(q * 16 + 4 * lg + r) * 512 + p * 16 + lr] = acc[q * 4 + p][r];
    }
}

// ---------------------------------------------------------------------------
// Stage 2 (FUSED): row softmax (side 0, mask m2 -> PF0) and column softmax
// (side 1, mask m1 -> PF1). S32 read-only. Dense 16KB PF tiles:
// tile (b,t16) at byte (b*32+t16)*16384;
// intra-tile byte = (lw>>2)*1024 + (lw&3)*256 + (row&15)*16, lw = k/8.
// ---------------------------------------------------------------------------
__global__ __launch_bounds__(256)
void softmax_both(const float* __restrict__ S32, float* __restrict__ PF0,
                  float* __restrict__ PF1,
                  const float* __restrict__ m1, const float* __restrict__ m2)
{
    const int bi   = blockIdx.x;           // 1024
    const int side = bi >> 9;
    const int idx  = bi & 511;
    const int b    = idx >> 4;
    const int t    = idx & 15;

    const int tid  = threadIdx.x;

    if (side == 0) {
        const int lane = tid & 63;
        const int w    = tid >> 6;
        __shared__ float mask_r[LKN];
        mask_r[tid] = m2[tid * BB + b];
        mask_r[tid + 256] = m2[(tid + 256) * BB + b];
        __syncthreads();

        float mk[8];
        #pragma unroll
        for (int j = 0; j < 8; ++j) mk[j] = mask_r[lane * 8 + j];

        const int row0 = t * 32 + w * 8;

        f4 fa[8], fb[8];
        #pragma unroll
        for (int rr = 0; rr < 8; ++rr) {
            const float* rp = S32 + ((size_t)b * 512 + row0 + rr) * 512 + lane * 8;
            fa[rr] = *(const f4*)rp;
            fb[rr] = *(const f4*)(rp + 4);
        }

        #pragma unroll
        for (int rr = 0; rr < 8; ++rr) {
            float f[8] = {fa[rr][0], fa[rr][1], fa[rr][2], fa[rr][3],
                          fb[rr][0], fb[rr][1], fb[rr][2], fb[rr][3]};
            float m = fmaxf(fmaxf(fmaxf(f[0], f[1]), fmaxf(f[2], f[3])),
                            fmaxf(fmaxf(f[4], f[5]), fmaxf(f[6], f[7])));
            #pragma unroll
            for (int d = 1; d <= 32; d <<= 1) m = fmaxf(m, __shfl_xor(m, d));
            float e[8], s = 0.f;
            #pragma unroll
            for (int j = 0; j < 8; ++j) { e[j] = __expf(f[j] - m) * mk[j]; s += e[j]; }
            #pragma unroll
            for (int d = 1; d <= 32; d <<= 1) s += __shfl_xor(s, d);
            const float inv = 1.f / (s + 1e-8f);
            H8 o;
            o.u[0] = pk2(e[0] * inv, e[1] * inv); o.u[1] = pk2(e[2] * inv, e[3] * inv);
            o.u[2] = pk2(e[4] * inv, e[5] * inv); o.u[3] = pk2(e[6] * inv, e[7] * inv);
            const int row = row0 + rr;
            char* base = (char*)PF0 + ((size_t)b * 32 + (row >> 4)) * 16384;
            *(half8*)(base + (lane >> 2) * 1024 + (lane & 3) * 256 + (row & 15) * 16) = o.h;
        }
    } else {
        __shared__ float raw[32][513];
        __shared__ float mask_c[LKN];
        __shared__ float redm[8][32];
        __shared__ float reds[8][32];

        mask_c[tid] = m1[tid * BB + b];
        mask_c[tid + 256] = m1[(tid + 256) * BB + b];

        {
            const float* sbase = S32 + ((size_t)b * 512 + (tid >> 3)) * 512 + t * 32 + (tid & 7) * 4;
            f4 vv[16];
            #pragma unroll
            for (int it = 0; it < 8; ++it) gloadf4(vv[it], sbase + (size_t)it * 32 * 512);
            asm volatile("s_waitcnt vmcnt(0)" ::: "memory");
            __builtin_amdgcn_sched_barrier(0);
            #pragma unroll
            for (int it = 8; it < 16; ++it) gloadf4(vv[it], sbase + (size_t)it * 32 * 512);
            #pragma unroll
            for (int it = 0; it < 8; ++it) {
                const int row = it * 32 + (tid >> 3);
                const int c0  = (tid & 7) * 4;
                raw[c0 + 0][row] = vv[it][0]; raw[c0 + 1][row] = vv[it][1];
                raw[c0 + 2][row] = vv[it][2]; raw[c0 + 3][row] = vv[it][3];
            }
            asm volatile("s_waitcnt vmcnt(0)" ::: "memory");
            __builtin_amdgcn_sched_barrier(0);
            #pragma unroll
            for (int it = 8; it < 16; ++it) {
                const int row = it * 32 + (tid >> 3);
                const int c0  = (tid & 7) * 4;
                raw[c0 + 0][row] = vv[it][0]; raw[c0 + 1][row] = vv[it][1];
                raw[c0 + 2][row] = vv[it][2]; raw[c0 + 3][row] = vv[it][3];
            }
        }
        __syncthreads();

        const int col = tid & 31;
        const int seg = tid >> 5;

        float m = -3.0e38f;
        #pragma unroll
        for (int r = 0; r < 64; ++r) m = fmaxf(m, raw[col][seg * 64 + r]);
        redm[seg][col] = m;
        __syncthreads();
        float M = redm[0][col];
        #pragma unroll
        for (int s2 = 1; s2 < 8; ++s2) M = fmaxf(M, redm[s2][col]);

        float s = 0.f;
        #pragma unroll
        for (int r = 0; r < 64; ++r) {
            const int row = seg * 64 + r;
            s += __expf(raw[col][row] - M) * mask_c[row];
        }
        reds[seg][col] = s;
        __syncthreads();
        float L = 0.f;
        #pragma unroll
        for (int s2 = 0; s2 < 8; ++s2) L += reds[s2][col];
        const float inv = 1.f / (L + 1e-8f);

        const int col_g = t * 32 + col;
        char* pfb = (char*)PF1 + ((size_t)b * 32 + (col_g >> 4)) * 16384;
        #pragma unroll
        for (int kc = 0; kc < 8; ++kc) {
            const int k0 = seg * 64 + kc * 8;
            float e[8];
            #pragma unroll
            for (int j = 0; j < 8; ++j)
                e[j] = __expf(raw[col][k0 + j] - M) * mask_c[k0 + j] * inv;
            H8 o;
            o.u[0] = pk2(e[0], e[1]); o.u[1] = pk2(e[2], e[3]);
            o.u[2] = pk2(e[4], e[5]); o.u[3] = pk2(e[6], e[7]);
            const int lw = seg * 8 + kc;
            *(half8*)(pfb + (lw >> 2) * 1024 + (lw & 3) * 256 + (col_g & 15) * 16) = o.h;
        }
    }
}

// ---------------------------------------------------------------------------
// Stage 3: OUT = P.V — 128-row tiles (1024 blocks). P-slice staged ONCE per
// block per ks2 into a 2x8KB LDS ping-pong; V register double-buffered with
// counted vmcnt (3 V loads always in flight).
// ---------------------------------------------------------------------------
__global__ __launch_bounds__(256)
void pv_frag(const float* __restrict__ PF0, const float* __restrict__ PF1,
             const _Float16* __restrict__ xv1, const _Float16* __restrict__ xv2,
             float* __restrict__ o1, float* __restrict__ o2)
{
    const int i    = blockIdx.x;           // 1024
    const int xcd  = i & 7;
    const int j    = i >> 3;               // 0..127
    const int lt   = j & 3;                // fastest: 4 l-tiles of 128 rows share V
    const int dq   = (j >> 2) & 3;         // 4 d-quarters of 192
    const int side = (j >> 4) & 1;
    const int b    = xcd * 4 + (j >> 5);   // slowest
    const int l0   = lt * 128;

    const float* __restrict__ PF    = side ? PF1 : PF0;
    const _Float16* __restrict__ VF = side ? xv1 : xv2;   // V = other side
    float* __restrict__ OUT         = side ? o2 : o1;

    const int tid  = threadIdx.x;
    const int lane = tid & 63;
    const int w    = tid >> 6;
    const int lr   = lane & 15;
    const int lg   = lane >> 4;

    __shared__ char plds[2][8192];         // ping-pong P slices (8KB = 8 q-tiles x 1KB)

    const char* psA = (const char*)PF + ((size_t)b * 32 + lt * 8 + 2 * w)     * 16384 + lane * 16;
    const char* psB = (const char*)PF + ((size_t)b * 32 + lt * 8 + 2 * w + 1) * 16384 + lane * 16;
    const _Float16* vbase = VF + (((size_t)b * 48 + dq * 12 + w * 3) * 16) * 512 + lane * 8;

    f4 acc[24];                            // [q(0..7)][nt(0..2)]
    #pragma unroll
    for (int t = 0; t < 24; ++t) acc[t] = f4{0.f, 0.f, 0.f, 0.f};

    half8 vf[2][3];
    half8 pA, pB;

    // prologue: stage P(0) into plds[0]; issue V(0)
    gload16(pA, (const _Float16*)psA);
    gload16(pB, (const _Float16*)psB);
    asm volatile("s_waitcnt vmcnt(0)" ::: "memory");
    __builtin_amdgcn_sched_barrier(0);
    *(half8*)(plds[0] + (2 * w) * 1024 + lane * 16)     = pA;
    *(half8*)(plds[0] + (2 * w + 1) * 1024 + lane * 16) = pB;
    #pragma unroll
    for (int nt = 0; nt < 3; ++nt) gload16(vf[0][nt], vbase + (size_t)nt * 16 * 512);
    __syncthreads();

    #pragma unroll
    for (int ks2 = 0; ks2 < 16; ++ks2) {
        const int cur = ks2 & 1;
        const int nxt = cur ^ 1;

        // a. read P fragments for this ks2 from LDS (all 8 q-tiles)
        half8 pa[8];
        #pragma unroll
        for (int q = 0; q < 8; ++q)
            pa[q] = *(const half8*)(plds[cur] + q * 1024 + lane * 16);

        // b. issue next P slice + next V batch
        if (ks2 < 15) {
            gload16(pA, (const _Float16*)(psA + (ks2 + 1) * 1024));
            gload16(pB, (const _Float16*)(psB + (ks2 + 1) * 1024));
            #pragma unroll
            for (int nt = 0; nt < 3; ++nt)
                gload16(vf[nxt][nt], vbase + ((size_t)nt * 16 + ks2 + 1) * 512);
            asm volatile("s_waitcnt vmcnt(5)" ::: "memory");   // V(cur) complete
        } else {
            asm volatile("s_waitcnt vmcnt(0)" ::: "memory");
        }
        __builtin_amdgcn_sched_barrier(0);

        // c. MFMA
        __builtin_amdgcn_s_setprio(1);
        #pragma unroll
        for (int nt = 0; nt < 3; ++nt)
            #pragma unroll
            for (int q = 0; q < 8; ++q)
                acc[q * 3 + nt] = __builtin_amdgcn_mfma_f32_16x16x32_f16(pa[q], vf[cur][nt], acc[q * 3 + nt], 0, 0, 0);
        __builtin_amdgcn_s_setprio(0);

        // d. write next P slice to the other buffer, then barrier
        if (ks2 < 15) {
            asm volatile("s_waitcnt vmcnt(3)" ::: "memory");   // P regs done
            __builtin_amdgcn_sched_barrier(0);
            *(half8*)(plds[nxt] + (2 * w) * 1024 + lane * 16)     = pA;
            *(half8*)(plds[nxt] + (2 * w + 1) * 1024 + lane * 16) = pB;
        }
        __syncthreads();
    }

    #pragma unroll
    for (int q = 0; q < 8; ++q)
        #pragma unroll
        for (int nt = 0; nt < 3; ++nt)
            #pragma unroll
            for (int r = 0; r < 4; ++r)
                OUT[((size_t)(l0 + q * 16 + 4 * lg + r) * BB + b) * DD + dq * 192 + (w * 3 + nt) * 16 + lr]
                    = acc[q * 3 + nt][r];
}

// ---------------------------------------------------------------------------
// Fallback (f32 direct, no ws).
// ---------------------------------------------------------------------------
__global__ __launch_bounds__(256)
void coatt_flash_f32(const float* __restrict__ x1, const float* __restrict__ m1,
                     const float* __restrict__ x2, const float* __restrict__ m2,
                     float* __restrict__ o1, float* __restrict__ o2)
{
    const int i    = blockIdx.x;
    const int xcd  = i & 7;
    const int j    = i >> 3;
    const int pair = xcd * 8 + (j >> 5);
    const int qt   = j & 31;
    const int side = pair >> 5;
    const int b    = pair & 31;

    const float* __restrict__ Q   = side ? x2 : x1;
    const float* __restrict__ K   = side ? x1 : x2;
    const float* __restrict__ MK  = side ? m1 : m2;
    float* __restrict__       OUT = side ? o2 : o1;

    const int tid  = threadIdx.x;
    const int lane = tid & 63;
    const int w    = tid >> 6;
    const int lr   = lane & 15;
    const int lg   = lane >> 4;
    const int q0 = qt * 16;
    const int d0 = w * (DD / 4);

    __shared__ float sred[4][16][36];
    __shared__ float mask_s[LKN];
    for (int t = tid; t < LKN; t += 256) mask_s[t] = MK[t * BB + b];

    half8 qf[6];
    {
        const float* qrow = Q + ((q0 + lr) * BB + b) * DD + d0 + lg * 8;
        #pragma unroll
        for (int ks = 0; ks < 6; ++ks) {
            f4 a = *(const f4*)(qrow + ks * 32);
            f4 c = *(const f4*)(qrow + ks * 32 + 4);
            qf[ks] = cvt8(a, c);
        }
    }
    f4 acc[12];
    #pragma unroll
    for (int t = 0; t < 12; ++t) acc[t] = f4{0.f, 0.f, 0.f, 0.f};
    float Mrun = -3.0e38f, Lrun = 0.f;
    for (int kt = 0; kt < 16; ++kt) {
        const int k0 = kt * 32;
        f4 s0 = {0.f,0.f,0.f,0.f}, s1 = {0.f,0.f,0.f,0.f};
        {
            const float* kb0 = K + ((k0 + lr) * BB + b) * DD + d0 + lg * 8;
            const float* kb1 = kb0 + 16 * BB * DD;
            #pragma unroll
            for (int ks = 0; ks < 6; ++ks) {
                f4 a0 = *(const f4*)(kb0 + ks * 32);
                f4 c0 = *(const f4*)(kb0 + ks * 32 + 4);
                s0 = __builtin_amdgcn_mfma_f32_16x16x32_f16(qf[ks], cvt8(a0, c0), s0, 0, 0, 0);
                f4 a1 = *(const f4*)(kb1 + ks * 32);
                f4 c1 = *(const f4*)(kb1 + ks * 32 + 4);
                s1 = __builtin_amdgcn_mfma_f32_16x16x32_f16(qf[ks], cvt8(a1, c1), s1, 0, 0, 0);
            }
        }
        __syncthreads();
        #pragma unroll
        for (int r = 0; r < 4; ++r) {
            sred[w][4 * lg + r][lr]      = s0[r];
            sred[w][4 * lg + r][16 + lr] = s1[r];
        }
        __syncthreads();
        f4 sa = {0.f,0.f,0.f,0.f}, sb = {0.f,0.f,0.f,0.f};
        #pragma unroll
        for (int ww = 0; ww < 4; ++ww) {
            sa += *(const f4*)&sred[ww][lr][lg * 8];
            sb += *(const f4*)&sred[ww][lr][lg * 8 + 4];
        }
        float tmax = fmaxf(fmaxf(fmaxf(sa[0], sa[1]), fmaxf(sa[2], sa[3])),
                           fmaxf(fmaxf(sb[0], sb[1]), fmaxf(sb[2], sb[3])));
        tmax = fmaxf(tmax, __shfl_xor(tmax, 16));
        tmax = fmaxf(tmax, __shfl_xor(tmax, 32));
        const float Mnew  = fmaxf(Mrun, tmax);
        const float scale = __expf(Mrun - Mnew);
        float p[8];
        float psum = 0.f;
        const float* mrow = &mask_s[k0 + lg * 8];
        #pragma unroll
        for (int t = 0; t < 4; ++t) { p[t]     = __expf(sa[t] - Mnew) * mrow[t];     psum += p[t]; }
        #pragma unroll
        for (int t = 0; t < 4; ++t) { p[4 + t] = __expf(sb[t] - Mnew) * mrow[4 + t]; psum += p[4 + t]; }
        psum += __shfl_xor(psum, 16);
        psum += __shfl_xor(psum, 32);
        Lrun = Lrun * scale + psum;
        Mrun = Mnew;
        H8 pf;
        pf.u[0] = pk2(p[0], p[1]); pf.u[1] = pk2(p[2], p[3]);
        pf.u[2] = pk2(p[4], p[5]); pf.u[3] = pk2(p[6], p[7]);
        float sc[4];
        #pragma unroll
        for (int r = 0; r < 4; ++r) sc[r] = __shfl(scale, (lane & 48) + 4 * lg + r);
        #pragma unroll
        for (int t = 0; t < 12; ++t) {
            acc[t][0] *= sc[0]; acc[t][1] *= sc[1];
            acc[t][2] *= sc[2]; acc[t][3] *= sc[3];
        }
        const float* vb = K + ((k0 + lg * 8) * BB + b) * DD + d0 + lr;
        #pragma unroll
        for (int nt = 0; nt < 12; ++nt) {
            const float* vp = vb + nt * 16;
            float vv[8];
            #pragma unroll
            for (int t = 0; t < 8; ++t) vv[t] = vp[t * BB * DD];
            H8 vf;
            vf.u[0] = pk2(vv[0], vv[1]); vf.u[1] = pk2(vv[2], vv[3]);
            vf.u[2] = pk2(vv[4], vv[5]); vf.u[3] = pk2(vv[6], vv[7]);
            acc[nt] = __builtin_amdgcn_mfma_f32_16x16x32_f16(pf.h, vf.h, acc[nt], 0, 0, 0);
        }
    }
    float il[4];
    {
        const float inv = 1.f / (Lrun + 1e-8f);
        #pragma unroll
        for (int r = 0; r < 4; ++r) il[r] = __shfl(inv, (lane & 48) + 4 * lg + r);
    }
    #pragma unroll
    for (int nt = 0; nt < 12; ++nt) {
        #pragma unroll
        for (int r = 0; r < 4; ++r) {
            OUT[((q0 + 4 * lg + r) * BB + b) * DD + d0 + nt * 16 + lr] = acc[nt][r] * il[r];
        }
    }
}

extern "C" void kernel_launch(void* const* d_in, const int* in_sizes, int n_in,
                              void* d_out, int out_size, void* d_ws, size_t ws_size,
                              hipStream_t stream) {
    (void)in_sizes; (void)n_in; (void)out_size;
    const float* x1 = (const float*)d_in[0];
    const float* m1 = (const float*)d_in[1];
    const float* x2 = (const float*)d_in[2];
    const float* m2 = (const float*)d_in[3];
    float* o1 = (float*)d_out;
    float* o2 = o1 + (size_t)LQ * BB * DD;

    const size_t ELEMS = (size_t)LQ * BB * DD;           // 12.58M
    const size_t SELEM = (size_t)BB * 512 * 512;         // 8.39M
    const size_t NEED  = 4 * ELEMS * sizeof(_Float16)    // XF + XV (100.7 MB)
                       + SELEM * sizeof(float);          // S f32 (33.6 MB) = 134.2 MB

    if (ws_size >= NEED) {
        _Float16* xf1 = (_Float16*)d_ws;
        _Float16* xf2 = xf1 + ELEMS;
        _Float16* xv1 = xf2 + ELEMS;
        _Float16* xv2 = xv1 + ELEMS;
        float*    S32 = (float*)(xv2 + ELEMS);           // dedicated 33.6 MB
        // Dense P buffers overlay the XF region (dead after gemm_s):
        float*    PF0 = (float*)d_ws;
        float*    PF1 = (float*)((char*)d_ws + (size_t)32 * 32 * 16384);
        prep_pack<<<3072, 512, 0, stream>>>(x1, x2, xf1, xf2, xv1, xv2);
        gemm_s<<<512, 256, 0, stream>>>(xf1, xf2, S32);
        softmax_both<<<1024, 256, 0, stream>>>(S32, PF0, PF1, m1, m2);
        pv_frag<<<1024, 256, 0, stream>>>(PF0, PF1, xv1, xv2, o1, o2);
    } else {
        coatt_flash_f32<<<2048, 256, 0, stream>>>(x1, m1, x2, m2, o1, o2);
    }
}

// Round 26
// 129.607 us; speedup vs baseline: 1.2259x; 1.2259x over previous
//
#include <hip/hip_runtime.h>

// Problem constants
#define LQ  512
#define LKN 512
#define BB  32
#define DD  768

typedef float    f4     __attribute__((ext_vector_type(4)));
typedef _Float16 half8  __attribute__((ext_vector_type(8)));
typedef _Float16 half4  __attribute__((ext_vector_type(4)));
typedef __fp16   fp16x2 __attribute__((ext_vector_type(2)));

union H8 { half8 h; unsigned int u[4]; };

__device__ __forceinline__ unsigned int pk2(float a, float b) {
    union { fp16x2 h; unsigned int u; } c;
    c.h = __builtin_amdgcn_cvt_pkrtz(a, b);
    return c.u;
}
__device__ __forceinline__ half8 cvt8(f4 a, f4 b) {
    H8 r;
    r.u[0] = pk2(a[0], a[1]); r.u[1] = pk2(a[2], a[3]);
    r.u[2] = pk2(b[0], b[1]); r.u[3] = pk2(b[2], b[3]);
    return r.h;
}

// Forced-in-flight global loads (volatile asm cannot be sunk by the scheduler).
__device__ __forceinline__ void gload16(half8& dst, const _Float16* p) {
    asm volatile("global_load_dwordx4 %0, %1, off" : "=v"(dst) : "v"(p));
}
__device__ __forceinline__ void gloadf4(f4& dst, const float* p) {
    asm volatile("global_load_dwordx4 %0, %1, off" : "=v"(dst) : "v"(p));
}

// ---------------------------------------------------------------------------
// prep_pack: 3072 blocks x 512 threads, 64 l x 128 d per block. REGULAR
// stores (r25's nontemporal stores broke producer->consumer L2 chaining:
// gemm_s's XF re-reads went HBM-cold, +25us). RNE via (_Float16) casts.
// ---------------------------------------------------------------------------
__global__ __launch_bounds__(512)
void prep_pack(const float* __restrict__ x1, const float* __restrict__ x2,
               _Float16* __restrict__ xf1, _Float16* __restrict__ xf2,
               _Float16* __restrict__ xv1, _Float16* __restrict__ xv2)
{
    const int bi   = blockIdx.x;            // 3072
    const int side = bi / 1536;
    const int rem  = bi % 1536;
    const int b    = rem / 48;
    const int rem2 = rem % 48;
    const int l0   = (rem2 / 6) * 64;
    const int d0   = (rem2 % 6) * 128;

    const float* __restrict__ X  = side ? x2  : x1;
    _Float16* __restrict__    XF = side ? xf2 : xf1;
    _Float16* __restrict__    XV = side ? xv2 : xv1;

    __shared__ _Float16 T[64][136];         // 64 x 128 data + pad

    const int tid = threadIdx.x;            // 0..511
    {
        const int r  = tid >> 4;            // 0..31
        const int c8 = (tid & 15) * 8;      // 0..120
        const float* src = X + ((size_t)(l0 + r) * BB + b) * DD + d0 + c8;
        f4 v0, v1, v2, v3;
        gloadf4(v0, src);
        gloadf4(v1, src + 4);
        gloadf4(v2, src + (size_t)32 * BB * DD);        // row r+32
        gloadf4(v3, src + (size_t)32 * BB * DD + 4);
        asm volatile("s_waitcnt vmcnt(2)" ::: "memory"); // first row pair done
        __builtin_amdgcn_sched_barrier(0);
        {
            half4 ha, hb;
            ha[0] = (_Float16)v0[0]; ha[1] = (_Float16)v0[1];
            ha[2] = (_Float16)v0[2]; ha[3] = (_Float16)v0[3];
            hb[0] = (_Float16)v1[0]; hb[1] = (_Float16)v1[1];
            hb[2] = (_Float16)v1[2]; hb[3] = (_Float16)v1[3];
            *(half4*)&T[r][c8]     = ha;
            *(half4*)&T[r][c8 + 4] = hb;
        }
        asm volatile("s_waitcnt vmcnt(0)" ::: "memory");
        __builtin_amdgcn_sched_barrier(0);
        {
            half4 ha, hb;
            ha[0] = (_Float16)v2[0]; ha[1] = (_Float16)v2[1];
            ha[2] = (_Float16)v2[2]; ha[3] = (_Float16)v2[3];
            hb[0] = (_Float16)v3[0]; hb[1] = (_Float16)v3[1];
            hb[2] = (_Float16)v3[2]; hb[3] = (_Float16)v3[3];
            *(half4*)&T[r + 32][c8]     = ha;
            *(half4*)&T[r + 32][c8 + 4] = hb;
        }
    }
    __syncthreads();
    // XF: fragment-packed (A/B operand for QK^T): 1024 chunks, 2 per thread
    #pragma unroll
    for (int c2 = tid; c2 < 1024; c2 += 512) {
        const int dhalf = c2 >> 9;          // 0..1
        const int t16l  = (c2 >> 7) & 3;
        const int ksl   = (c2 >> 6) & 1;
        const int ln    = c2 & 63;
        half8 v = *(const half8*)&T[t16l * 16 + (ln & 15)][dhalf * 64 + ksl * 32 + (ln >> 4) * 8];
        const size_t t16g = (size_t)(l0 >> 4) + t16l;
        const size_t ksg  = (size_t)(d0 >> 5) + dhalf * 2 + ksl;
        *(half8*)(XF + (((size_t)b * 32 + t16g) * 24 + ksg) * 512 + ln * 8) = v;
    }
    // XV: B-fragment-packed V: 1024 chunks, 2 per thread
    #pragma unroll
    for (int c2 = tid; c2 < 1024; c2 += 512) {
        const int dtl  = c2 >> 7;           // 0..7
        const int ks2l = (c2 >> 6) & 1;
        const int ln   = c2 & 63;
        half8 v;
        #pragma unroll
        for (int jj = 0; jj < 8; ++jj)
            v[jj] = T[ks2l * 32 + (ln >> 4) * 8 + jj][dtl * 16 + (ln & 15)];
        const size_t dtg  = (size_t)(d0 >> 4) + dtl;
        const size_t ks2g = (size_t)(l0 >> 5) + ks2l;
        *(half8*)(XV + (((size_t)b * 48 + dtg) * 16 + ks2g) * 512 + ln * 8) = v;
    }
}

// ---------------------------------------------------------------------------
// Stage 1: S = x1.x2^T (f32), 128x128 tile/block, no LDS.
// ---------------------------------------------------------------------------
__global__ __launch_bounds__(256, 3)
void gemm_s(const _Float16* __restrict__ xf1, const _Float16* __restrict__ xf2,
            float* __restrict__ S)
{
    const int i   = blockIdx.x;            // 512
    const int xcd = i & 7;
    const int j   = i >> 3;                // 0..63
    const int t   = j & 15;                // tile fastest
    const int b   = xcd * 4 + (j >> 4);    // b slowest
    const int lt  = t >> 2, mt = t & 3;
    const int l0b = lt * 128, m0b = mt * 128;

    const int tid  = threadIdx.x;
    const int lane = tid & 63;
    const int w    = tid >> 6;
    const int wl   = w >> 1, wm = w & 1;
    const int lr   = lane & 15;
    const int lg   = lane >> 4;

    f4 acc[16];
    #pragma unroll
    for (int t2 = 0; t2 < 16; ++t2) acc[t2] = f4{0.f, 0.f, 0.f, 0.f};

    {
        const _Float16* ab = xf1 + (((size_t)b * 32 + lt * 8 + wl * 4) * 24) * 512 + lane * 8;
        const _Float16* bb = xf2 + (((size_t)b * 32 + mt * 8 + wm * 4) * 24) * 512 + lane * 8;
        __builtin_amdgcn_s_setprio(1);
        #pragma unroll
        for (int ks = 0; ks < 24; ++ks) {
            half8 aF[4], bF[4];
            #pragma unroll
            for (int q = 0; q < 4; ++q) {
                aF[q] = *(const half8*)(ab + ((size_t)q * 24 + ks) * 512);
                bF[q] = *(const half8*)(bb + ((size_t)q * 24 + ks) * 512);
            }
            #pragma unroll
            for (int q = 0; q < 4; ++q)
                #pragma unroll
                for (int p = 0; p < 4; ++p)
                    acc[q * 4 + p] = __builtin_amdgcn_mfma_f32_16x16x32_f16(aF[q], bF[p], acc[q * 4 + p], 0, 0, 0);
        }
        __builtin_amdgcn_s_setprio(0);
    }

    {
        float* srow = S + ((size_t)b * 512 + l0b + wl * 64) * 512 + m0b + wm * 64;
        #pragma unroll
        for (int q = 0; q < 4; ++q)
            #pragma unroll
            for (int p = 0; p < 4; ++p)
                #pragma unroll
                for (int r = 0; r < 4; ++r)
                    srow[(size_t)(q * 16 + 4 * lg + r) * 512 + p * 16 + lr] = acc[q * 4 + p][r];
    }
}

// ---------------------------------------------------------------------------
// Stage 2 (FUSED): row softmax (side 0, mask m2 -> PF0) and column softmax
// (side 1, mask m1 -> PF1). S32 read-only. Dense 16KB PF tiles:
// tile (b,t16) at byte (b*32+t16)*16384;
// intra-tile byte = (lw>>2)*1024 + (lw&3)*256 + (row&15)*16, lw = k/8.
// ---------------------------------------------------------------------------
__global__ __launch_bounds__(256)
void softmax_both(const float* __restrict__ S32, float* __restrict__ PF0,
                  float* __restrict__ PF1,
                  const float* __restrict__ m1, const float* __restrict__ m2)
{
    const int bi   = blockIdx.x;           // 1024
    const int side = bi >> 9;
    const int idx  = bi & 511;
    const int b    = idx >> 4;
    const int t    = idx & 15;

    const int tid  = threadIdx.x;

    if (side == 0) {
        const int lane = tid & 63;
        const int w    = tid >> 6;
        __shared__ float mask_r[LKN];
        mask_r[tid] = m2[tid * BB + b];
        mask_r[tid + 256] = m2[(tid + 256) * BB + b];
        __syncthreads();

        float mk[8];
        #pragma unroll
        for (int j = 0; j < 8; ++j) mk[j] = mask_r[lane * 8 + j];

        const int row0 = t * 32 + w * 8;

        f4 fa[8], fb[8];
        #pragma unroll
        for (int rr = 0; rr < 8; ++rr) {
            const float* rp = S32 + ((size_t)b * 512 + row0 + rr) * 512 + lane * 8;
            fa[rr] = *(const f4*)rp;
            fb[rr] = *(const f4*)(rp + 4);
        }

        #pragma unroll
        for (int rr = 0; rr < 8; ++rr) {
            float f[8] = {fa[rr][0], fa[rr][1], fa[rr][2], fa[rr][3],
                          fb[rr][0], fb[rr][1], fb[rr][2], fb[rr][3]};
            float m = fmaxf(fmaxf(fmaxf(f[0], f[1]), fmaxf(f[2], f[3])),
                            fmaxf(fmaxf(f[4], f[5]), fmaxf(f[6], f[7])));
            #pragma unroll
            for (int d = 1; d <= 32; d <<= 1) m = fmaxf(m, __shfl_xor(m, d));
            float e[8], s = 0.f;
            #pragma unroll
            for (int j = 0; j < 8; ++j) { e[j] = __expf(f[j] - m) * mk[j]; s += e[j]; }
            #pragma unroll
            for (int d = 1; d <= 32; d <<= 1) s += __shfl_xor(s, d);
            const float inv = 1.f / (s + 1e-8f);
            H8 o;
            o.u[0] = pk2(e[0] * inv, e[1] * inv); o.u[1] = pk2(e[2] * inv, e[3] * inv);
            o.u[2] = pk2(e[4] * inv, e[5] * inv); o.u[3] = pk2(e[6] * inv, e[7] * inv);
            const int row = row0 + rr;
            char* base = (char*)PF0 + ((size_t)b * 32 + (row >> 4)) * 16384;
            *(half8*)(base + (lane >> 2) * 1024 + (lane & 3) * 256 + (row & 15) * 16) = o.h;
        }
    } else {
        __shared__ float raw[32][513];
        __shared__ float mask_c[LKN];
        __shared__ float redm[8][32];
        __shared__ float reds[8][32];

        mask_c[tid] = m1[tid * BB + b];
        mask_c[tid + 256] = m1[(tid + 256) * BB + b];

        {
            const float* sbase = S32 + ((size_t)b * 512 + (tid >> 3)) * 512 + t * 32 + (tid & 7) * 4;
            f4 vv[16];
            #pragma unroll
            for (int it = 0; it < 8; ++it) gloadf4(vv[it], sbase + (size_t)it * 32 * 512);
            asm volatile("s_waitcnt vmcnt(0)" ::: "memory");
            __builtin_amdgcn_sched_barrier(0);
            #pragma unroll
            for (int it = 8; it < 16; ++it) gloadf4(vv[it], sbase + (size_t)it * 32 * 512);
            #pragma unroll
            for (int it = 0; it < 8; ++it) {
                const int row = it * 32 + (tid >> 3);
                const int c0  = (tid & 7) * 4;
                raw[c0 + 0][row] = vv[it][0]; raw[c0 + 1][row] = vv[it][1];
                raw[c0 + 2][row] = vv[it][2]; raw[c0 + 3][row] = vv[it][3];
            }
            asm volatile("s_waitcnt vmcnt(0)" ::: "memory");
            __builtin_amdgcn_sched_barrier(0);
            #pragma unroll
            for (int it = 8; it < 16; ++it) {
                const int row = it * 32 + (tid >> 3);
                const int c0  = (tid & 7) * 4;
                raw[c0 + 0][row] = vv[it][0]; raw[c0 + 1][row] = vv[it][1];
                raw[c0 + 2][row] = vv[it][2]; raw[c0 + 3][row] = vv[it][3];
            }
        }
        __syncthreads();

        const int col = tid & 31;
        const int seg = tid >> 5;

        float m = -3.0e38f;
        #pragma unroll
        for (int r = 0; r < 64; ++r) m = fmaxf(m, raw[col][seg * 64 + r]);
        redm[seg][col] = m;
        __syncthreads();
        float M = redm[0][col];
        #pragma unroll
        for (int s2 = 1; s2 < 8; ++s2) M = fmaxf(M, redm[s2][col]);

        float s = 0.f;
        #pragma unroll
        for (int r = 0; r < 64; ++r) {
            const int row = seg * 64 + r;
            s += __expf(raw[col][row] - M) * mask_c[row];
        }
        reds[seg][col] = s;
        __syncthreads();
        float L = 0.f;
        #pragma unroll
        for (int s2 = 0; s2 < 8; ++s2) L += reds[s2][col];
        const float inv = 1.f / (L + 1e-8f);

        const int col_g = t * 32 + col;
        char* pfb = (char*)PF1 + ((size_t)b * 32 + (col_g >> 4)) * 16384;
        #pragma unroll
        for (int kc = 0; kc < 8; ++kc) {
            const int k0 = seg * 64 + kc * 8;
            float e[8];
            #pragma unroll
            for (int j = 0; j < 8; ++j)
                e[j] = __expf(raw[col][k0 + j] - M) * mask_c[k0 + j] * inv;
            H8 o;
            o.u[0] = pk2(e[0], e[1]); o.u[1] = pk2(e[2], e[3]);
            o.u[2] = pk2(e[4], e[5]); o.u[3] = pk2(e[6], e[7]);
            const int lw = seg * 8 + kc;
            *(half8*)(pfb + (lw >> 2) * 1024 + (lw & 3) * 256 + (col_g & 15) * 16) = o.h;
        }
    }
}

// ---------------------------------------------------------------------------
// Stage 3: OUT = P.V — 128-row tiles (1024 blocks). P-slice staged ONCE per
// block per ks2 into a 2x8KB LDS ping-pong; V register double-buffered with
// counted vmcnt (3 V loads always in flight).
// ---------------------------------------------------------------------------
__global__ __launch_bounds__(256)
void pv_frag(const float* __restrict__ PF0, const float* __restrict__ PF1,
             const _Float16* __restrict__ xv1, const _Float16* __restrict__ xv2,
             float* __restrict__ o1, float* __restrict__ o2)
{
    const int i    = blockIdx.x;           // 1024
    const int xcd  = i & 7;
    const int j    = i >> 3;               // 0..127
    const int lt   = j & 3;                // fastest: 4 l-tiles of 128 rows share V
    const int dq   = (j >> 2) & 3;         // 4 d-quarters of 192
    const int side = (j >> 4) & 1;
    const int b    = xcd * 4 + (j >> 5);   // slowest
    const int l0   = lt * 128;

    const float* __restrict__ PF    = side ? PF1 : PF0;
    const _Float16* __restrict__ VF = side ? xv1 : xv2;   // V = other side
    float* __restrict__ OUT         = side ? o2 : o1;

    const int tid  = threadIdx.x;
    const int lane = tid & 63;
    const int w    = tid >> 6;
    const int lr   = lane & 15;
    const int lg   = lane >> 4;

    __shared__ char plds[2][8192];         // ping-pong P slices (8KB = 8 q-tiles x 1KB)

    const char* psA = (const char*)PF + ((size_t)b * 32 + lt * 8 + 2 * w)     * 16384 + lane * 16;
    const char* psB = (const char*)PF + ((size_t)b * 32 + lt * 8 + 2 * w + 1) * 16384 + lane * 16;
    const _Float16* vbase = VF + (((size_t)b * 48 + dq * 12 + w * 3) * 16) * 512 + lane * 8;

    f4 acc[24];                            // [q(0..7)][nt(0..2)]
    #pragma unroll
    for (int t = 0; t < 24; ++t) acc[t] = f4{0.f, 0.f, 0.f, 0.f};

    half8 vf[2][3];
    half8 pA, pB;

    // prologue: stage P(0) into plds[0]; issue V(0)
    gload16(pA, (const _Float16*)psA);
    gload16(pB, (const _Float16*)psB);
    asm volatile("s_waitcnt vmcnt(0)" ::: "memory");
    __builtin_amdgcn_sched_barrier(0);
    *(half8*)(plds[0] + (2 * w) * 1024 + lane * 16)     = pA;
    *(half8*)(plds[0] + (2 * w + 1) * 1024 + lane * 16) = pB;
    #pragma unroll
    for (int nt = 0; nt < 3; ++nt) gload16(vf[0][nt], vbase + (size_t)nt * 16 * 512);
    __syncthreads();

    #pragma unroll
    for (int ks2 = 0; ks2 < 16; ++ks2) {
        const int cur = ks2 & 1;
        const int nxt = cur ^ 1;

        // a. read P fragments for this ks2 from LDS (all 8 q-tiles)
        half8 pa[8];
        #pragma unroll
        for (int q = 0; q < 8; ++q)
            pa[q] = *(const half8*)(plds[cur] + q * 1024 + lane * 16);

        // b. issue next P slice + next V batch
        if (ks2 < 15) {
            gload16(pA, (const _Float16*)(psA + (ks2 + 1) * 1024));
            gload16(pB, (const _Float16*)(psB + (ks2 + 1) * 1024));
            #pragma unroll
            for (int nt = 0; nt < 3; ++nt)
                gload16(vf[nxt][nt], vbase + ((size_t)nt * 16 + ks2 + 1) * 512);
            asm volatile("s_waitcnt vmcnt(5)" ::: "memory");   // V(cur) complete
        } else {
            asm volatile("s_waitcnt vmcnt(0)" ::: "memory");
        }
        __builtin_amdgcn_sched_barrier(0);

        // c. MFMA
        __builtin_amdgcn_s_setprio(1);
        #pragma unroll
        for (int nt = 0; nt < 3; ++nt)
            #pragma unroll
            for (int q = 0; q < 8; ++q)
                acc[q * 3 + nt] = __builtin_amdgcn_mfma_f32_16x16x32_f16(pa[q], vf[cur][nt], acc[q * 3 + nt], 0, 0, 0);
        __builtin_amdgcn_s_setprio(0);

        // d. write next P slice to the other buffer, then barrier
        if (ks2 < 15) {
            asm volatile("s_waitcnt vmcnt(3)" ::: "memory");   // P regs done
            __builtin_amdgcn_sched_barrier(0);
            *(half8*)(plds[nxt] + (2 * w) * 1024 + lane * 16)     = pA;
            *(half8*)(plds[nxt] + (2 * w + 1) * 1024 + lane * 16) = pB;
        }
        __syncthreads();
    }

    #pragma unroll
    for (int q = 0; q < 8; ++q)
        #pragma unroll
        for (int nt = 0; nt < 3; ++nt)
            #pragma unroll
            for (int r = 0; r < 4; ++r)
                OUT[((size_t)(l0 + q * 16 + 4 * lg + r) * BB + b) * DD + dq * 192 + (w * 3 + nt) * 16 + lr]
                    = acc[q * 3 + nt][r];
}

// ---------------------------------------------------------------------------
// Fallback (f32 direct, no ws).
// ---------------------------------------------------------------------------
__global__ __launch_bounds__(256)
void coatt_flash_f32(const float* __restrict__ x1, const float* __restrict__ m1,
                     const float* __restrict__ x2, const float* __restrict__ m2,
                     float* __restrict__ o1, float* __restrict__ o2)
{
    const int i    = blockIdx.x;
    const int xcd  = i & 7;
    const int j    = i >> 3;
    const int pair = xcd * 8 + (j >> 5);
    const int qt   = j & 31;
    const int side = pair >> 5;
    const int b    = pair & 31;

    const float* __restrict__ Q   = side ? x2 : x1;
    const float* __restrict__ K   = side ? x1 : x2;
    const float* __restrict__ MK  = side ? m1 : m2;
    float* __restrict__       OUT = side ? o2 : o1;

    const int tid  = threadIdx.x;
    const int lane = tid & 63;
    const int w    = tid >> 6;
    const int lr   = lane & 15;
    const int lg   = lane >> 4;
    const int q0 = qt * 16;
    const int d0 = w * (DD / 4);

    __shared__ float sred[4][16][36];
    __shared__ float mask_s[LKN];
    for (int t = tid; t < LKN; t += 256) mask_s[t] = MK[t * BB + b];

    half8 qf[6];
    {
        const float* qrow = Q + ((q0 + lr) * BB + b) * DD + d0 + lg * 8;
        #pragma unroll
        for (int ks = 0; ks < 6; ++ks) {
            f4 a = *(const f4*)(qrow + ks * 32);
            f4 c = *(const f4*)(qrow + ks * 32 + 4);
            qf[ks] = cvt8(a, c);
        }
    }
    f4 acc[12];
    #pragma unroll
    for (int t = 0; t < 12; ++t) acc[t] = f4{0.f, 0.f, 0.f, 0.f};
    float Mrun = -3.0e38f, Lrun = 0.f;
    for (int kt = 0; kt < 16; ++kt) {
        const int k0 = kt * 32;
        f4 s0 = {0.f,0.f,0.f,0.f}, s1 = {0.f,0.f,0.f,0.f};
        {
            const float* kb0 = K + ((k0 + lr) * BB + b) * DD + d0 + lg * 8;
            const float* kb1 = kb0 + 16 * BB * DD;
            #pragma unroll
            for (int ks = 0; ks < 6; ++ks) {
                f4 a0 = *(const f4*)(kb0 + ks * 32);
                f4 c0 = *(const f4*)(kb0 + ks * 32 + 4);
                s0 = __builtin_amdgcn_mfma_f32_16x16x32_f16(qf[ks], cvt8(a0, c0), s0, 0, 0, 0);
                f4 a1 = *(const f4*)(kb1 + ks * 32);
                f4 c1 = *(const f4*)(kb1 + ks * 32 + 4);
                s1 = __builtin_amdgcn_mfma_f32_16x16x32_f16(qf[ks], cvt8(a1, c1), s1, 0, 0, 0);
            }
        }
        __syncthreads();
        #pragma unroll
        for (int r = 0; r < 4; ++r) {
            sred[w][4 * lg + r][lr]      = s0[r];
            sred[w][4 * lg + r][16 + lr] = s1[r];
        }
        __syncthreads();
        f4 sa = {0.f,0.f,0.f,0.f}, sb = {0.f,0.f,0.f,0.f};
        #pragma unroll
        for (int ww = 0; ww < 4; ++ww) {
            sa += *(const f4*)&sred[ww][lr][lg * 8];
            sb += *(const f4*)&sred[ww][lr][lg * 8 + 4];
        }
        float tmax = fmaxf(fmaxf(fmaxf(sa[0], sa[1]), fmaxf(sa[2], sa[3])),
                           fmaxf(fmaxf(sb[0], sb[1]), fmaxf(sb[2], sb[3])));
        tmax = fmaxf(tmax, __shfl_xor(tmax, 16));
        tmax = fmaxf(tmax, __shfl_xor(tmax, 32));
        const float Mnew  = fmaxf(Mrun, tmax);
        const float scale = __expf(Mrun - Mnew);
        float p[8];
        float psum = 0.f;
        const float* mrow = &mask_s[k0 + lg * 8];
        #pragma unroll
        for (int t = 0; t < 4; ++t) { p[t]     = __expf(sa[t] - Mnew) * mrow[t];     psum += p[t]; }
        #pragma unroll
        for (int t = 0; t < 4; ++t) { p[4 + t] = __expf(sb[t] - Mnew) * mrow[4 + t]; psum += p[4 + t]; }
        psum += __shfl_xor(psum, 16);
        psum += __shfl_xor(psum, 32);
        Lrun = Lrun * scale + psum;
        Mrun = Mnew;
        H8 pf;
        pf.u[0] = pk2(p[0], p[1]); pf.u[1] = pk2(p[2], p[3]);
        pf.u[2] = pk2(p[4], p[5]); pf.u[3] = pk2(p[6], p[7]);
        float sc[4];
        #pragma unroll
        for (int r = 0; r < 4; ++r) sc[r] = __shfl(scale, (lane & 48) + 4 * lg + r);
        #pragma unroll
        for (int t = 0; t < 12; ++t) {
            acc[t][0] *= sc[0]; acc[t][1] *= sc[1];
            acc[t][2] *= sc[2]; acc[t][3] *= sc[3];
        }
        const float* vb = K + ((k0 + lg * 8) * BB + b) * DD + d0 + lr;
        #pragma unroll
        for (int nt = 0; nt < 12; ++nt) {
            const float* vp = vb + nt * 16;
            float vv[8];
            #pragma unroll
            for (int t = 0; t < 8; ++t) vv[t] = vp[t * BB * DD];
            H8 vf;
            vf.u[0] = pk2(vv[0], vv[1]); vf.u[1] = pk2(vv[2], vv[3]);
            vf.u[2] = pk2(vv[4], vv[5]); vf.u[3] = pk2(vv[6], vv[7]);
            acc[nt] = __builtin_amdgcn_mfma_f32_16x16x32_f16(pf.h, vf.h, acc[nt], 0, 0, 0);
        }
    }
    float il[4];
    {
        const float inv = 1.f / (Lrun + 1e-8f);
        #pragma unroll
        for (int r = 0; r < 4; ++r) il[r] = __shfl(inv, (lane & 48) + 4 * lg + r);
    }
    #pragma unroll
    for (int nt = 0; nt < 12; ++nt) {
        #pragma unroll
        for (int r = 0; r < 4; ++r) {
            OUT[((q0 + 4 * lg + r) * BB + b) * DD + d0 + nt * 16 + lr] = acc[nt][r] * il[r];
        }
    }
}

extern "C" void kernel_launch(void* const* d_in, const int* in_sizes, int n_in,
                              void* d_out, int out_size, void* d_ws, size_t ws_size,
                              hipStream_t stream) {
    (void)in_sizes; (void)n_in; (void)out_size;
    const float* x1 = (const float*)d_in[0];
    const float* m1 = (const float*)d_in[1];
    const float* x2 = (const float*)d_in[2];
    const float* m2 = (const float*)d_in[3];
    float* o1 = (float*)d_out;
    float* o2 = o1 + (size_t)LQ * BB * DD;

    const size_t ELEMS = (size_t)LQ * BB * DD;           // 12.58M
    const size_t SELEM = (size_t)BB * 512 * 512;         // 8.39M
    const size_t NEED  = 4 * ELEMS * sizeof(_Float16)    // XF + XV (100.7 MB)
                       + SELEM * sizeof(float);          // S f32 (33.6 MB) = 134.2 MB

    if (ws_size >= NEED) {
        _Float16* xf1 = (_Float16*)d_ws;
        _Float16* xf2 = xf1 + ELEMS;
        _Float16* xv1 = xf2 + ELEMS;
        _Float16* xv2 = xv1 + ELEMS;
        float*    S32 = (float*)(xv2 + ELEMS);           // dedicated 33.6 MB
        // Dense P buffers overlay the XF region (dead after gemm_s):
        float*    PF0 = (float*)d_ws;
        float*    PF1 = (float*)((char*)d_ws + (size_t)32 * 32 * 16384);
        prep_pack<<<3072, 512, 0, stream>>>(x1, x2, xf1, xf2, xv1, xv2);
        gemm_s<<<512, 256, 0, stream>>>(xf1, xf2, S32);
        softmax_both<<<1024, 256, 0, stream>>>(S32, PF0, PF1, m1, m2);
        pv_frag<<<1024, 256, 0, stream>>>(PF0, PF1, xv1, xv2, o1, o2);
    } else {
        coatt_flash_f32<<<2048, 256, 0, stream>>>(x1, m1, x2, m2, o1, o2);
    }
}